// Round 10
// baseline (417.603 us; speedup 1.0000x reference)
//
#include <hip/hip_runtime.h>

typedef __bf16 bf16_t;
typedef __bf16 bf16x8 __attribute__((ext_vector_type(8)));
typedef float f32x4 __attribute__((ext_vector_type(4)));

#define B_SZ 4
#define NHEADS 16
#define L_SEQ 1365
#define LP_V 1408                         // padded leading dim of transposed V (16B-aligned rows)
#define C_DIM 1024
#define HD 64
#define M_ROWS (B_SZ * L_SEQ)            // 5460
#define K_DIM 1024
#define BHL (B_SZ * NHEADS * L_SEQ)      // 87360

__device__ __forceinline__ f32x4 zero4() {
    f32x4 z; z[0] = 0.f; z[1] = 0.f; z[2] = 0.f; z[3] = 0.f; return z;
}

// async global->LDS, 16 bytes per lane. LDS dest must be wave-uniform base + lane*16.
__device__ __forceinline__ void gload_lds16(const void* g, void* l) {
    __builtin_amdgcn_global_load_lds(
        (const __attribute__((address_space(1))) void*)(uintptr_t)g,
        (__attribute__((address_space(3))) void*)(unsigned int)(uintptr_t)l,
        16, 0, 0);
}

__device__ __forceinline__ int vislen(int row) {
    // block-causal visible length; cum([1,4,16,64,256,1024]) = [1,5,21,85,341,1365]
    if (row < 1) return 1;
    if (row < 5) return 5;
    if (row < 21) return 21;
    if (row < 85) return 85;
    if (row < 341) return 341;
    return 1365;
}

// ---------------- Kernel 0: fused fp32 -> bf16 convert of x, Wqkv, Wp
#define N8_X  (5591040 / 8)
#define N8_WQ (3145728 / 8)
#define N8_WP (1048576 / 8)
__global__ __launch_bounds__(256) void cvt_all(const float* __restrict__ x,
                                               const float* __restrict__ wq,
                                               const float* __restrict__ wp,
                                               bf16_t* __restrict__ xo,
                                               bf16_t* __restrict__ wqo,
                                               bf16_t* __restrict__ wpo) {
    int i = blockIdx.x * 256 + threadIdx.x;
    const float* in;
    bf16_t* out;
    if (i < N8_X) { in = x; out = xo; }
    else if (i < N8_X + N8_WQ) { i -= N8_X; in = wq; out = wqo; }
    else if (i < N8_X + N8_WQ + N8_WP) { i -= N8_X + N8_WQ; in = wp; out = wpo; }
    else return;
    const float* p = in + (size_t)i * 8;
    f32x4 a = *(const f32x4*)p;
    f32x4 b = *(const f32x4*)(p + 4);
    bf16x8 r;
    r[0] = (bf16_t)a[0]; r[1] = (bf16_t)a[1]; r[2] = (bf16_t)a[2]; r[3] = (bf16_t)a[3];
    r[4] = (bf16_t)b[0]; r[5] = (bf16_t)b[1]; r[6] = (bf16_t)b[2]; r[7] = (bf16_t)b[3];
    *(bf16x8*)(out + (size_t)i * 8) = r;
}

// ---------------- Kernel 1: QKV GEMM with FUSED norm+scale+RoPE epilogue.
// XCD-swizzled 1-D grid: 1032 = 8 XCD x (3 ntile x 43 mtile).
__global__ __launch_bounds__(256) void qkv_gemm(const bf16_t* __restrict__ A,
                                                const bf16_t* __restrict__ Bw,
                                                const float* __restrict__ qbias,
                                                const float* __restrict__ vbias,
                                                const float* __restrict__ rc,
                                                const float* __restrict__ rs,
                                                const float* __restrict__ sml,
                                                bf16_t* __restrict__ qo,
                                                bf16_t* __restrict__ ko,
                                                bf16_t* __restrict__ vt) {
    __shared__ __align__(16) bf16_t As[128 * 32];
    __shared__ __align__(16) bf16_t Bs[128 * 32];
    const int tid = threadIdx.x;
    const int w = tid >> 6, lane = tid & 63, quad = lane >> 4, l16 = lane & 15;
    const int id = blockIdx.x;
    const int xcd = id & 7, s = id >> 3;
    const int ntile = xcd * 3 + s / 43;          // per-XCD B-slice: 3x128 cols (0.75 MB)
    const int mtile = s - (s / 43) * 43;
    const int mw = (w >> 1) * 64, nw = (w & 1) * 64;

    int ar0 = mtile * 128 + (tid >> 2); if (ar0 > M_ROWS - 1) ar0 = M_ROWS - 1;
    int ar1 = ar0 + 64;                 if (ar1 > M_ROWS - 1) ar1 = M_ROWS - 1;
    const int nr0 = ntile * 128 + (tid >> 2);
    const int cc = (tid & 3) * 8;

    f32x4 acc[4][4];
#pragma unroll
    for (int i = 0; i < 4; ++i)
#pragma unroll
        for (int j = 0; j < 4; ++j) acc[i][j] = zero4();

    for (int k0 = 0; k0 < K_DIM; k0 += 32) {
        __syncthreads();
        gload_lds16(A + (size_t)ar0 * K_DIM + k0 + cc, (char*)As + tid * 16);
        gload_lds16(A + (size_t)ar1 * K_DIM + k0 + cc, (char*)As + tid * 16 + 4096);
        gload_lds16(Bw + (size_t)nr0 * K_DIM + k0 + cc, (char*)Bs + tid * 16);
        gload_lds16(Bw + (size_t)(nr0 + 64) * K_DIM + k0 + cc, (char*)Bs + tid * 16 + 4096);
        __syncthreads();
        bf16x8 af[4], bfr[4];
#pragma unroll
        for (int mi = 0; mi < 4; ++mi)
            af[mi] = *(const bf16x8*)&As[(mw + mi * 16 + l16) * 32 + quad * 8];
#pragma unroll
        for (int ni = 0; ni < 4; ++ni)
            bfr[ni] = *(const bf16x8*)&Bs[(nw + ni * 16 + l16) * 32 + quad * 8];
#pragma unroll
        for (int mi = 0; mi < 4; ++mi)
#pragma unroll
            for (int ni = 0; ni < 4; ++ni)
                acc[mi][ni] = __builtin_amdgcn_mfma_f32_16x16x32_bf16(af[mi], bfr[ni], acc[mi][ni], 0, 0, 0);
    }

    const int three = ntile >> 3;                    // 0=q, 1=k, 2=v (uniform per block)
    const int h = (((ntile & 7) * 128 + nw) >> 6);   // head index (uniform per wave)

    if (three == 2) {
        // V: bias + coalesced store to (B,H,L,hd)
#pragma unroll
        for (int ni = 0; ni < 4; ++ni) {
            int d = ni * 16 + l16;
            float bv = vbias[h * 64 + d];
#pragma unroll
            for (int mi = 0; mi < 4; ++mi)
#pragma unroll
                for (int r = 0; r < 4; ++r) {
                    int grow = mtile * 128 + mw + mi * 16 + quad * 4 + r;
                    if (grow < M_ROWS) {
                        int b_ = grow / L_SEQ;
                        int l = grow - b_ * L_SEQ;
                        vt[(((size_t)(b_ * NHEADS + h)) * L_SEQ + l) * HD + d] =
                            (bf16_t)(acc[mi][ni][r] + bv);
                    }
                }
        }
    } else {
        float scale = 1.f;
        if (three == 0) scale = __expf(fminf(sml[h], 4.6051702f));  // log(100)
        float bias[4];
#pragma unroll
        for (int ni = 0; ni < 4; ++ni)
            bias[ni] = (three == 0) ? qbias[h * 64 + ni * 16 + l16] : 0.f;
        bf16_t* dst = (three == 0) ? qo : ko;
#pragma unroll
        for (int mi = 0; mi < 4; ++mi)
#pragma unroll
            for (int r = 0; r < 4; ++r) {
                int grow = mtile * 128 + mw + mi * 16 + quad * 4 + r;
                float vv[4];
                float ss = 0.f;
#pragma unroll
                for (int ni = 0; ni < 4; ++ni) {
                    vv[ni] = acc[mi][ni][r] + bias[ni];
                    ss += vv[ni] * vv[ni];
                }
                ss += __shfl_xor(ss, 1); ss += __shfl_xor(ss, 2);
                ss += __shfl_xor(ss, 4); ss += __shfl_xor(ss, 8);
                float inv = scale * rsqrtf(fmaxf(ss, 1e-24f));
                int gc = grow < M_ROWS ? grow : M_ROWS - 1;
                int b_ = gc / L_SEQ;
                int l = gc - b_ * L_SEQ;
#pragma unroll
                for (int ni = 0; ni < 4; ++ni) {
                    float vn = vv[ni] * inv;
                    float pp = __shfl_xor(vn, 1);
                    int ti = l * 32 + ni * 8 + (l16 >> 1);
                    float c = rc[ti], s2 = rs[ti];
                    float ov = (l16 & 1) ? (s2 * pp + c * vn) : (c * vn - s2 * pp);
                    if (grow < M_ROWS)
                        dst[(((size_t)(b_ * NHEADS + h)) * L_SEQ + l) * HD + ni * 16 + l16] =
                            (bf16_t)ov;
                }
            }
    }
}

// ---------------- Kernel 1b: V transpose (B,H,L,hd) -> (B,H,hd,LP_V), 64x64 LDS tiles
__global__ __launch_bounds__(256) void vtrans(const bf16_t* __restrict__ in,
                                              bf16_t* __restrict__ out) {
    __shared__ bf16_t t[64][64];
    const int lt = blockIdx.x * 64, bh = blockIdx.y;
    const int tid = threadIdx.x;
#pragma unroll
    for (int it = 0; it < 2; ++it) {                    // two passes: rows 0-31, 32-63
        const int r = (tid >> 3) + it * 32, c8 = (tid & 7) * 8;
        int l = lt + r; if (l > L_SEQ - 1) l = L_SEQ - 1;  // clamped rows -> pad, masked in attn
        bf16x8 v8 = *(const bf16x8*)(in + ((size_t)bh * L_SEQ + l) * HD + c8);
#pragma unroll
        for (int j = 0; j < 8; ++j) t[c8 + j][r] = v8[j];
    }
    __syncthreads();
#pragma unroll
    for (int it = 0; it < 2; ++it) {
        int c = tid + it * 256;                  // 0..511
        int d = c >> 3, off = (c & 7) * 8;
        bf16x8 o8 = *(const bf16x8*)&t[d][off];
        *(bf16x8*)(out + ((size_t)bh * HD + d) * LP_V + lt + off) = o8;
    }
}

// ---------------- Kernel 3: flash attention, no-max softmax, 16 q-rows per wave
// (max TLP, direct epilogue everywhere, no partials). XCD-swizzled 1-D grid:
// 1408 = 8 XCD x (8 bh x 22 gblk); per-XCD K/V set stays in its L2.
__global__ __launch_bounds__(256) void attn(const bf16_t* __restrict__ q,
                                            const bf16_t* __restrict__ k,
                                            const bf16_t* __restrict__ v,
                                            bf16_t* __restrict__ ao) {
    __shared__ __align__(16) bf16_t plds[4][16][72];   // per-wave transpose slices
    const int tid = threadIdx.x;
    const int w = tid >> 6, lane = tid & 63, quad = lane >> 4, l16 = lane & 15;
    const int bid = blockIdx.x;
    const int xcd = bid & 7, s0 = bid >> 3;      // s0 in [0,176)
    const int bh = (xcd << 3) + s0 / 22;
    const int gblk = s0 - (s0 / 22) * 22;
    const int g = gblk + 22 * w;                 // 16-row q-group; {light,heavy,heavy,heavy}
    if (g >= 86) return;                         // no barriers -> early exit safe
    const int qbase = g * 16;

    int mrow = qbase + l16;
    int mc = mrow < L_SEQ ? mrow : (L_SEQ - 1);
    const bf16_t* qp = q + ((size_t)bh * L_SEQ + mc) * HD + quad * 8;
    bf16x8 aq0 = *(const bf16x8*)(qp);
    bf16x8 aq1 = *(const bf16x8*)(qp + 32);

    f32x4 o[4];
    o[0] = zero4(); o[1] = zero4(); o[2] = zero4(); o[3] = zero4();
    float l_i[4] = {0.f, 0.f, 0.f, 0.f};
    int visr[4];
#pragma unroll
    for (int r = 0; r < 4; ++r) visr[r] = vislen(qbase + quad * 4 + r);
    const int minvis = vislen(qbase);            // wave-uniform lower bound

    int rl = qbase + 15; if (rl > L_SEQ - 1) rl = L_SEQ - 1;
    const int ntk = (vislen(rl) + 63) >> 6;

    const bf16_t* kb = k + (size_t)bh * L_SEQ * HD + (size_t)l16 * HD + quad * 8;
    const bf16_t* vb = v + ((size_t)bh * HD + l16) * LP_V + quad * 8;

    for (int kt = 0; kt < ntk; ++kt) {
        const int kvb = kt * 64;
        // K fragments (rows unclamped: OOB rows read adjacent ws memory, masked below)
        const bf16_t* kp = kb + (size_t)kvb * HD;
        bf16x8 kf0[4], kf1[4];
#pragma unroll
        for (int nb = 0; nb < 4; ++nb) {
            kf0[nb] = *(const bf16x8*)(kp + nb * (16 * HD));
            kf1[nb] = *(const bf16x8*)(kp + nb * (16 * HD) + 32);
        }
        f32x4 s[4];
#pragma unroll
        for (int nb = 0; nb < 4; ++nb) {
            s[nb] = zero4();
            s[nb] = __builtin_amdgcn_mfma_f32_16x16x32_bf16(aq0, kf0[nb], s[nb], 0, 0, 0);
            s[nb] = __builtin_amdgcn_mfma_f32_16x16x32_bf16(aq1, kf1[nb], s[nb], 0, 0, 0);
        }

        if (kvb + 64 <= minvis) {
            // fully visible tile: no masking at all
#pragma unroll
            for (int nb = 0; nb < 4; ++nb)
#pragma unroll
                for (int r = 0; r < 4; ++r) {
                    float p = __expf(s[nb][r]);
                    l_i[r] += p;
                    plds[w][quad * 4 + r][nb * 16 + l16] = (bf16_t)p;
                }
        } else {
#pragma unroll
            for (int nb = 0; nb < 4; ++nb) {
                int col = kvb + nb * 16 + l16;
#pragma unroll
                for (int r = 0; r < 4; ++r) {
                    float e = __expf(s[nb][r]);
                    float p = (col < visr[r]) ? e : 0.f;
                    l_i[r] += p;
                    plds[w][quad * 4 + r][nb * 16 + l16] = (bf16_t)p;
                }
            }
        }

        bf16x8 ap0 = *(const bf16x8*)&plds[w][l16][quad * 8];
        bf16x8 ap1 = *(const bf16x8*)&plds[w][l16][32 + quad * 8];

        const bf16_t* vp = v + ((size_t)bh * HD) * LP_V + kvb + quad * 8;
#pragma unroll
        for (int nb = 0; nb < 4; ++nb) {
            const bf16_t* vpn = vp + (size_t)(nb * 16 + l16) * LP_V;
            bf16x8 v0 = *(const bf16x8*)(vpn);       // pad cols have p=0, inert
            bf16x8 v1 = *(const bf16x8*)(vpn + 32);
            o[nb] = __builtin_amdgcn_mfma_f32_16x16x32_bf16(ap0, v0, o[nb], 0, 0, 0);
            o[nb] = __builtin_amdgcn_mfma_f32_16x16x32_bf16(ap1, v1, o[nb], 0, 0, 0);
        }
    }

    // epilogue: reduce row-sums across the 16 column-lanes, scale, store (B, L, H*hd)
    const int b_ = bh >> 4, hh = bh & 15;
#pragma unroll
    for (int r = 0; r < 4; ++r) {
        float ls = l_i[r];
#pragma unroll
        for (int off = 1; off < 16; off <<= 1) ls += __shfl_xor(ls, off);
        int rowq = qbase + quad * 4 + r;
        if (rowq < L_SEQ) {
            float inv = 1.f / ls;
#pragma unroll
            for (int nb = 0; nb < 4; ++nb) {
                int d = nb * 16 + l16;
                size_t di = ((size_t)(b_ * L_SEQ + rowq)) * C_DIM + hh * HD + d;
                ao[di] = (bf16_t)(o[nb][r] * inv);
            }
        }
    }
}

// ---------------- Kernel 4: projection GEMM (128x128 tile), fp32 out + bias
// XCD-swizzled 1-D grid: 344 = 8 XCD x 43 mtile (1 ntile per XCD).
__global__ __launch_bounds__(256) void proj_gemm(const bf16_t* __restrict__ A,
                                                 const bf16_t* __restrict__ Bw,
                                                 const float* __restrict__ bias,
                                                 float* __restrict__ out) {
    __shared__ __align__(16) bf16_t As[128 * 32];
    __shared__ __align__(16) bf16_t Bs[128 * 32];
    const int tid = threadIdx.x;
    const int w = tid >> 6, lane = tid & 63, quad = lane >> 4, l16 = lane & 15;
    const int id = blockIdx.x;
    const int ntile = id & 7, mtile = id >> 3;
    const int mw = (w >> 1) * 64, nw = (w & 1) * 64;

    int ar0 = mtile * 128 + (tid >> 2); if (ar0 > M_ROWS - 1) ar0 = M_ROWS - 1;
    int ar1 = ar0 + 64;                 if (ar1 > M_ROWS - 1) ar1 = M_ROWS - 1;
    const int nr0 = ntile * 128 + (tid >> 2);
    const int cc = (tid & 3) * 8;

    f32x4 acc[4][4];
#pragma unroll
    for (int i = 0; i < 4; ++i)
#pragma unroll
        for (int j = 0; j < 4; ++j) acc[i][j] = zero4();

    for (int k0 = 0; k0 < K_DIM; k0 += 32) {
        __syncthreads();
        gload_lds16(A + (size_t)ar0 * K_DIM + k0 + cc, (char*)As + tid * 16);
        gload_lds16(A + (size_t)ar1 * K_DIM + k0 + cc, (char*)As + tid * 16 + 4096);
        gload_lds16(Bw + (size_t)nr0 * K_DIM + k0 + cc, (char*)Bs + tid * 16);
        gload_lds16(Bw + (size_t)(nr0 + 64) * K_DIM + k0 + cc, (char*)Bs + tid * 16 + 4096);
        __syncthreads();
        bf16x8 af[4], bfr[4];
#pragma unroll
        for (int mi = 0; mi < 4; ++mi)
            af[mi] = *(const bf16x8*)&As[(mw + mi * 16 + l16) * 32 + quad * 8];
#pragma unroll
        for (int ni = 0; ni < 4; ++ni)
            bfr[ni] = *(const bf16x8*)&Bs[(nw + ni * 16 + l16) * 32 + quad * 8];
#pragma unroll
        for (int mi = 0; mi < 4; ++mi)
#pragma unroll
            for (int ni = 0; ni < 4; ++ni)
                acc[mi][ni] = __builtin_amdgcn_mfma_f32_16x16x32_bf16(af[mi], bfr[ni], acc[mi][ni], 0, 0, 0);
    }

#pragma unroll
    for (int ni = 0; ni < 4; ++ni) {
        int ncol = ntile * 128 + nw + ni * 16 + l16;
        float bv = bias[ncol];
#pragma unroll
        for (int mi = 0; mi < 4; ++mi)
#pragma unroll
            for (int r = 0; r < 4; ++r) {
                int grow = mtile * 128 + mw + mi * 16 + quad * 4 + r;
                if (grow < M_ROWS)
                    out[(size_t)grow * C_DIM + ncol] = acc[mi][ni][r] + bv;
            }
    }
}

extern "C" void kernel_launch(void* const* d_in, const int* in_sizes, int n_in,
                              void* d_out, int out_size, void* d_ws, size_t ws_size,
                              hipStream_t stream) {
    const float* x    = (const float*)d_in[0];
    // d_in[1] = attn_bias (unused; mask computed analytically)
    const float* rc   = (const float*)d_in[2];
    const float* rs   = (const float*)d_in[3];
    const float* Wqkv = (const float*)d_in[4];
    const float* qb   = (const float*)d_in[5];
    const float* vb   = (const float*)d_in[6];
    const float* sml  = (const float*)d_in[7];
    const float* Wp   = (const float*)d_in[8];
    const float* bp   = (const float*)d_in[9];
    float* out = (float*)d_out;

    const size_t NQ   = (size_t)B_SZ * NHEADS * L_SEQ * HD;   // 5,591,040
    const size_t NVT  = (size_t)B_SZ * NHEADS * HD * LP_V;    // 5,767,168
    const size_t NX   = (size_t)M_ROWS * C_DIM;               // 5,591,040
    const size_t NWQ  = (size_t)3 * C_DIM * C_DIM;            // 3,145,728
    const size_t NWP  = (size_t)C_DIM * C_DIM;                // 1,048,576

    bf16_t* qo   = (bf16_t*)d_ws;
    bf16_t* ko   = qo + NQ;
    bf16_t* vtmp = ko + NQ;      // V in (B,H,L,hd), coalesced from qkv
    bf16_t* vo   = vtmp + NQ;    // V^T in (B,H,hd,LP_V)
    bf16_t* xb   = vo + NVT;     // reused as ao after qkv (same size NX == NQ)
    bf16_t* ao   = xb;
    bf16_t* wqb  = xb + NX;
    bf16_t* wpb  = wqb + NWQ;

    dim3 blk(256);
    const int ncvt = (N8_X + N8_WQ + N8_WP + 255) / 256;
    cvt_all<<<dim3(ncvt), blk, 0, stream>>>(x, Wqkv, Wp, xb, wqb, wpb);
    qkv_gemm<<<dim3(1032), blk, 0, stream>>>(xb, wqb, qb, vb, rc, rs, sml, qo, ko, vtmp);
    vtrans<<<dim3(22, 64), blk, 0, stream>>>(vtmp, vo);
    attn<<<dim3(1408), blk, 0, stream>>>(qo, ko, vo, ao);
    proj_gemm<<<dim3(344), blk, 0, stream>>>(ao, wpb, bp, out);
}

// Round 11
// 279.595 us; speedup vs baseline: 1.4936x; 1.4936x over previous
//
#include <hip/hip_runtime.h>

typedef __bf16 bf16_t;
typedef __bf16 bf16x8 __attribute__((ext_vector_type(8)));
typedef float f32x4 __attribute__((ext_vector_type(4)));

#define B_SZ 4
#define NHEADS 16
#define L_SEQ 1365
#define LP_V 1408                         // padded leading dim of transposed V (16B-aligned rows)
#define C_DIM 1024
#define HD 64
#define M_ROWS (B_SZ * L_SEQ)            // 5460
#define K_DIM 1024
#define BHL (B_SZ * NHEADS * L_SEQ)      // 87360

__device__ __forceinline__ f32x4 zero4() {
    f32x4 z; z[0] = 0.f; z[1] = 0.f; z[2] = 0.f; z[3] = 0.f; return z;
}

// async global->LDS, 16 bytes per lane. LDS dest must be wave-uniform base + lane*16.
__device__ __forceinline__ void gload_lds16(const void* g, void* l) {
    __builtin_amdgcn_global_load_lds(
        (const __attribute__((address_space(1))) void*)(uintptr_t)g,
        (__attribute__((address_space(3))) void*)(unsigned int)(uintptr_t)l,
        16, 0, 0);
}

__device__ __forceinline__ int vislen(int row) {
    // block-causal visible length; cum([1,4,16,64,256,1024]) = [1,5,21,85,341,1365]
    if (row < 1) return 1;
    if (row < 5) return 5;
    if (row < 21) return 21;
    if (row < 85) return 85;
    if (row < 341) return 341;
    return 1365;
}

// ---------------- Kernel 0: fused fp32 -> bf16 convert of x, Wqkv, Wp
#define N8_X  (5591040 / 8)
#define N8_WQ (3145728 / 8)
#define N8_WP (1048576 / 8)
__global__ __launch_bounds__(256) void cvt_all(const float* __restrict__ x,
                                               const float* __restrict__ wq,
                                               const float* __restrict__ wp,
                                               bf16_t* __restrict__ xo,
                                               bf16_t* __restrict__ wqo,
                                               bf16_t* __restrict__ wpo) {
    int i = blockIdx.x * 256 + threadIdx.x;
    const float* in;
    bf16_t* out;
    if (i < N8_X) { in = x; out = xo; }
    else if (i < N8_X + N8_WQ) { i -= N8_X; in = wq; out = wqo; }
    else if (i < N8_X + N8_WQ + N8_WP) { i -= N8_X + N8_WQ; in = wp; out = wpo; }
    else return;
    const float* p = in + (size_t)i * 8;
    f32x4 a = *(const f32x4*)p;
    f32x4 b = *(const f32x4*)(p + 4);
    bf16x8 r;
    r[0] = (bf16_t)a[0]; r[1] = (bf16_t)a[1]; r[2] = (bf16_t)a[2]; r[3] = (bf16_t)a[3];
    r[4] = (bf16_t)b[0]; r[5] = (bf16_t)b[1]; r[6] = (bf16_t)b[2]; r[7] = (bf16_t)b[3];
    *(bf16x8*)(out + (size_t)i * 8) = r;
}

// ---------------- Kernel 1: QKV GEMM with FUSED norm+scale+RoPE epilogue.
// XCD-swizzled 1-D grid: 1032 = 8 XCD x (3 ntile x 43 mtile).
__global__ __launch_bounds__(256) void qkv_gemm(const bf16_t* __restrict__ A,
                                                const bf16_t* __restrict__ Bw,
                                                const float* __restrict__ qbias,
                                                const float* __restrict__ vbias,
                                                const float* __restrict__ rc,
                                                const float* __restrict__ rs,
                                                const float* __restrict__ sml,
                                                bf16_t* __restrict__ qo,
                                                bf16_t* __restrict__ ko,
                                                bf16_t* __restrict__ vt) {
    __shared__ __align__(16) bf16_t As[128 * 32];
    __shared__ __align__(16) bf16_t Bs[128 * 32];
    const int tid = threadIdx.x;
    const int w = tid >> 6, lane = tid & 63, quad = lane >> 4, l16 = lane & 15;
    const int id = blockIdx.x;
    const int xcd = id & 7, s = id >> 3;
    const int ntile = xcd * 3 + s / 43;          // per-XCD B-slice: 3x128 cols (0.75 MB)
    const int mtile = s - (s / 43) * 43;
    const int mw = (w >> 1) * 64, nw = (w & 1) * 64;

    int ar0 = mtile * 128 + (tid >> 2); if (ar0 > M_ROWS - 1) ar0 = M_ROWS - 1;
    int ar1 = ar0 + 64;                 if (ar1 > M_ROWS - 1) ar1 = M_ROWS - 1;
    const int nr0 = ntile * 128 + (tid >> 2);
    const int cc = (tid & 3) * 8;

    f32x4 acc[4][4];
#pragma unroll
    for (int i = 0; i < 4; ++i)
#pragma unroll
        for (int j = 0; j < 4; ++j) acc[i][j] = zero4();

    for (int k0 = 0; k0 < K_DIM; k0 += 32) {
        __syncthreads();
        gload_lds16(A + (size_t)ar0 * K_DIM + k0 + cc, (char*)As + tid * 16);
        gload_lds16(A + (size_t)ar1 * K_DIM + k0 + cc, (char*)As + tid * 16 + 4096);
        gload_lds16(Bw + (size_t)nr0 * K_DIM + k0 + cc, (char*)Bs + tid * 16);
        gload_lds16(Bw + (size_t)(nr0 + 64) * K_DIM + k0 + cc, (char*)Bs + tid * 16 + 4096);
        __syncthreads();
        bf16x8 af[4], bfr[4];
#pragma unroll
        for (int mi = 0; mi < 4; ++mi)
            af[mi] = *(const bf16x8*)&As[(mw + mi * 16 + l16) * 32 + quad * 8];
#pragma unroll
        for (int ni = 0; ni < 4; ++ni)
            bfr[ni] = *(const bf16x8*)&Bs[(nw + ni * 16 + l16) * 32 + quad * 8];
#pragma unroll
        for (int mi = 0; mi < 4; ++mi)
#pragma unroll
            for (int ni = 0; ni < 4; ++ni)
                acc[mi][ni] = __builtin_amdgcn_mfma_f32_16x16x32_bf16(af[mi], bfr[ni], acc[mi][ni], 0, 0, 0);
    }

    const int three = ntile >> 3;                    // 0=q, 1=k, 2=v (uniform per block)
    const int h = (((ntile & 7) * 128 + nw) >> 6);   // head index (uniform per wave)

    if (three == 2) {
        // V: bias + coalesced store to (B,H,L,hd)
#pragma unroll
        for (int ni = 0; ni < 4; ++ni) {
            int d = ni * 16 + l16;
            float bv = vbias[h * 64 + d];
#pragma unroll
            for (int mi = 0; mi < 4; ++mi)
#pragma unroll
                for (int r = 0; r < 4; ++r) {
                    int grow = mtile * 128 + mw + mi * 16 + quad * 4 + r;
                    if (grow < M_ROWS) {
                        int b_ = grow / L_SEQ;
                        int l = grow - b_ * L_SEQ;
                        vt[(((size_t)(b_ * NHEADS + h)) * L_SEQ + l) * HD + d] =
                            (bf16_t)(acc[mi][ni][r] + bv);
                    }
                }
        }
    } else {
        float scale = 1.f;
        if (three == 0) scale = __expf(fminf(sml[h], 4.6051702f));  // log(100)
        float bias[4];
#pragma unroll
        for (int ni = 0; ni < 4; ++ni)
            bias[ni] = (three == 0) ? qbias[h * 64 + ni * 16 + l16] : 0.f;
        bf16_t* dst = (three == 0) ? qo : ko;
#pragma unroll
        for (int mi = 0; mi < 4; ++mi)
#pragma unroll
            for (int r = 0; r < 4; ++r) {
                int grow = mtile * 128 + mw + mi * 16 + quad * 4 + r;
                float vv[4];
                float ss = 0.f;
#pragma unroll
                for (int ni = 0; ni < 4; ++ni) {
                    vv[ni] = acc[mi][ni][r] + bias[ni];
                    ss += vv[ni] * vv[ni];
                }
                ss += __shfl_xor(ss, 1); ss += __shfl_xor(ss, 2);
                ss += __shfl_xor(ss, 4); ss += __shfl_xor(ss, 8);
                float inv = scale * rsqrtf(fmaxf(ss, 1e-24f));
                int gc = grow < M_ROWS ? grow : M_ROWS - 1;
                int b_ = gc / L_SEQ;
                int l = gc - b_ * L_SEQ;
#pragma unroll
                for (int ni = 0; ni < 4; ++ni) {
                    float vn = vv[ni] * inv;
                    float pp = __shfl_xor(vn, 1);
                    int ti = l * 32 + ni * 8 + (l16 >> 1);
                    float c = rc[ti], s2 = rs[ti];
                    float ov = (l16 & 1) ? (s2 * pp + c * vn) : (c * vn - s2 * pp);
                    if (grow < M_ROWS)
                        dst[(((size_t)(b_ * NHEADS + h)) * L_SEQ + l) * HD + ni * 16 + l16] =
                            (bf16_t)ov;
                }
            }
    }
}

// ---------------- Kernel 1b: V transpose (B,H,L,hd) -> (B,H,hd,LP_V), 64x64 LDS tiles
__global__ __launch_bounds__(256) void vtrans(const bf16_t* __restrict__ in,
                                              bf16_t* __restrict__ out) {
    __shared__ bf16_t t[64][64];
    const int lt = blockIdx.x * 64, bh = blockIdx.y;
    const int tid = threadIdx.x;
#pragma unroll
    for (int it = 0; it < 2; ++it) {                    // two passes: rows 0-31, 32-63
        const int r = (tid >> 3) + it * 32, c8 = (tid & 7) * 8;
        int l = lt + r; if (l > L_SEQ - 1) l = L_SEQ - 1;  // clamped rows -> pad, masked in attn
        bf16x8 v8 = *(const bf16x8*)(in + ((size_t)bh * L_SEQ + l) * HD + c8);
#pragma unroll
        for (int j = 0; j < 8; ++j) t[c8 + j][r] = v8[j];
    }
    __syncthreads();
#pragma unroll
    for (int it = 0; it < 2; ++it) {
        int c = tid + it * 256;                  // 0..511
        int d = c >> 3, off = (c & 7) * 8;
        bf16x8 o8 = *(const bf16x8*)&t[d][off];
        *(bf16x8*)(out + ((size_t)bh * HD + d) * LP_V + lt + off) = o8;
    }
}

// ---------------- Kernel 3: flash attention, no-max softmax, LDS-staged K/V shared
// by all 4 waves (m97-style: coalesced staging, ds_read_b128 fragments).
// Block = 128 q-rows x bh; wave handles 32 rows. XCD-swizzled 1-D grid:
// 704 = 8 XCD x (8 bh x 11 qg); per-XCD K/V set stays in its L2.
__global__ __launch_bounds__(256) void attn(const bf16_t* __restrict__ q,
                                            const bf16_t* __restrict__ k,
                                            const bf16_t* __restrict__ v,
                                            bf16_t* __restrict__ ao) {
    __shared__ __align__(16) bf16_t Ks[64][72];           // K tile  [kv][hd], +8 pad
    __shared__ __align__(16) bf16_t Vs[64][72];           // V^T tile [hd][kv], +8 pad
    __shared__ __align__(16) bf16_t plds[4][2][16][72];   // per-wave P transpose
    const int tid = threadIdx.x;
    const int w = tid >> 6, lane = tid & 63, quad = lane >> 4, l16 = lane & 15;
    const int bid = blockIdx.x;
    const int xcd = bid & 7, s0 = bid >> 3;      // s0 in [0,88)
    const int bh = (xcd << 3) + s0 / 11;
    const int qg = s0 - (s0 / 11) * 11;          // 128-row q-group [0,11)
    const int qbase = qg * 128 + w * 32;         // this wave's 32 rows

    bf16x8 aq[2][2];
#pragma unroll
    for (int h = 0; h < 2; ++h) {
        int mrow = qbase + h * 16 + l16;
        int mc = mrow < L_SEQ ? mrow : (L_SEQ - 1);
        const bf16_t* qp = q + ((size_t)bh * L_SEQ + mc) * HD + quad * 8;
        aq[h][0] = *(const bf16x8*)(qp);
        aq[h][1] = *(const bf16x8*)(qp + 32);
    }

    f32x4 o[2][4];
    float l_i[2][4];
    int visr[2][4];
#pragma unroll
    for (int h = 0; h < 2; ++h)
#pragma unroll
        for (int r = 0; r < 4; ++r) {
            o[h][r] = zero4();
            l_i[h][r] = 0.f;
            visr[h][r] = vislen(qbase + h * 16 + quad * 4 + r);
        }
    const int minvis = vislen(qbase);            // wave-uniform

    int rl = qg * 128 + 127; if (rl > L_SEQ - 1) rl = L_SEQ - 1;
    const int ntk = (vislen(rl) + 63) >> 6;      // block-uniform

    // staging coords: thread covers K row srow, 32B slice at scol
    const int srow = tid >> 2;                   // 0..63
    const int scol = (tid & 3) * 16;             // 0,16,32,48

    for (int kt = 0; kt < ntk; ++kt) {
        const int kvb = kt * 64;
        // issue global loads BEFORE the barrier (overlap the drain)
        const bf16_t* kp = k + ((size_t)bh * L_SEQ + kvb + srow) * HD + scol;
        const bf16_t* vp = v + ((size_t)bh * HD + srow) * LP_V + kvb + scol;
        bf16x8 k0 = *(const bf16x8*)(kp);
        bf16x8 k1 = *(const bf16x8*)(kp + 8);
        bf16x8 v0 = *(const bf16x8*)(vp);
        bf16x8 v1 = *(const bf16x8*)(vp + 8);
        __syncthreads();                         // previous tile's LDS reads done
        *(bf16x8*)&Ks[srow][scol] = k0;
        *(bf16x8*)&Ks[srow][scol + 8] = k1;
        *(bf16x8*)&Vs[srow][scol] = v0;
        *(bf16x8*)&Vs[srow][scol + 8] = v1;
        __syncthreads();

        bf16x8 kf0[4], kf1[4];
#pragma unroll
        for (int nb = 0; nb < 4; ++nb) {
            kf0[nb] = *(const bf16x8*)&Ks[nb * 16 + l16][quad * 8];
            kf1[nb] = *(const bf16x8*)&Ks[nb * 16 + l16][32 + quad * 8];
        }
        f32x4 s[2][4];
#pragma unroll
        for (int h = 0; h < 2; ++h)
#pragma unroll
            for (int nb = 0; nb < 4; ++nb) {
                s[h][nb] = zero4();
                s[h][nb] = __builtin_amdgcn_mfma_f32_16x16x32_bf16(aq[h][0], kf0[nb], s[h][nb], 0, 0, 0);
                s[h][nb] = __builtin_amdgcn_mfma_f32_16x16x32_bf16(aq[h][1], kf1[nb], s[h][nb], 0, 0, 0);
            }

        if (kvb + 64 <= minvis) {
            // fully visible tile: no masking
#pragma unroll
            for (int h = 0; h < 2; ++h)
#pragma unroll
                for (int nb = 0; nb < 4; ++nb)
#pragma unroll
                    for (int r = 0; r < 4; ++r) {
                        float p = __expf(s[h][nb][r]);
                        l_i[h][r] += p;
                        plds[w][h][quad * 4 + r][nb * 16 + l16] = (bf16_t)p;
                    }
        } else {
#pragma unroll
            for (int h = 0; h < 2; ++h)
#pragma unroll
                for (int nb = 0; nb < 4; ++nb) {
                    int col = kvb + nb * 16 + l16;
#pragma unroll
                    for (int r = 0; r < 4; ++r) {
                        float e = __expf(s[h][nb][r]);
                        float p = (col < visr[h][r]) ? e : 0.f;
                        l_i[h][r] += p;
                        plds[w][h][quad * 4 + r][nb * 16 + l16] = (bf16_t)p;
                    }
                }
        }

        bf16x8 ap[2][2];
#pragma unroll
        for (int h = 0; h < 2; ++h) {
            ap[h][0] = *(const bf16x8*)&plds[w][h][l16][quad * 8];
            ap[h][1] = *(const bf16x8*)&plds[w][h][l16][32 + quad * 8];
        }
#pragma unroll
        for (int nb = 0; nb < 4; ++nb) {
            bf16x8 vf0 = *(const bf16x8*)&Vs[nb * 16 + l16][quad * 8];
            bf16x8 vf1 = *(const bf16x8*)&Vs[nb * 16 + l16][32 + quad * 8];
#pragma unroll
            for (int h = 0; h < 2; ++h) {
                o[h][nb] = __builtin_amdgcn_mfma_f32_16x16x32_bf16(ap[h][0], vf0, o[h][nb], 0, 0, 0);
                o[h][nb] = __builtin_amdgcn_mfma_f32_16x16x32_bf16(ap[h][1], vf1, o[h][nb], 0, 0, 0);
            }
        }
    }

    // epilogue: reduce row-sums across the 16 column-lanes, scale, store (B, L, H*hd)
    const int b_ = bh >> 4, hh = bh & 15;
#pragma unroll
    for (int h = 0; h < 2; ++h)
#pragma unroll
        for (int r = 0; r < 4; ++r) {
            float ls = l_i[h][r];
#pragma unroll
            for (int off = 1; off < 16; off <<= 1) ls += __shfl_xor(ls, off);
            int rowq = qbase + h * 16 + quad * 4 + r;
            if (rowq < L_SEQ) {
                float inv = 1.f / ls;
#pragma unroll
                for (int nb = 0; nb < 4; ++nb) {
                    int d = nb * 16 + l16;
                    size_t di = ((size_t)(b_ * L_SEQ + rowq)) * C_DIM + hh * HD + d;
                    ao[di] = (bf16_t)(o[h][nb][r] * inv);
                }
            }
        }
}

// ---------------- Kernel 4: projection GEMM (128x128 tile), fp32 out + bias
// XCD-swizzled 1-D grid: 344 = 8 XCD x 43 mtile (1 ntile per XCD).
__global__ __launch_bounds__(256) void proj_gemm(const bf16_t* __restrict__ A,
                                                 const bf16_t* __restrict__ Bw,
                                                 const float* __restrict__ bias,
                                                 float* __restrict__ out) {
    __shared__ __align__(16) bf16_t As[128 * 32];
    __shared__ __align__(16) bf16_t Bs[128 * 32];
    const int tid = threadIdx.x;
    const int w = tid >> 6, lane = tid & 63, quad = lane >> 4, l16 = lane & 15;
    const int id = blockIdx.x;
    const int ntile = id & 7, mtile = id >> 3;
    const int mw = (w >> 1) * 64, nw = (w & 1) * 64;

    int ar0 = mtile * 128 + (tid >> 2); if (ar0 > M_ROWS - 1) ar0 = M_ROWS - 1;
    int ar1 = ar0 + 64;                 if (ar1 > M_ROWS - 1) ar1 = M_ROWS - 1;
    const int nr0 = ntile * 128 + (tid >> 2);
    const int cc = (tid & 3) * 8;

    f32x4 acc[4][4];
#pragma unroll
    for (int i = 0; i < 4; ++i)
#pragma unroll
        for (int j = 0; j < 4; ++j) acc[i][j] = zero4();

    for (int k0 = 0; k0 < K_DIM; k0 += 32) {
        __syncthreads();
        gload_lds16(A + (size_t)ar0 * K_DIM + k0 + cc, (char*)As + tid * 16);
        gload_lds16(A + (size_t)ar1 * K_DIM + k0 + cc, (char*)As + tid * 16 + 4096);
        gload_lds16(Bw + (size_t)nr0 * K_DIM + k0 + cc, (char*)Bs + tid * 16);
        gload_lds16(Bw + (size_t)(nr0 + 64) * K_DIM + k0 + cc, (char*)Bs + tid * 16 + 4096);
        __syncthreads();
        bf16x8 af[4], bfr[4];
#pragma unroll
        for (int mi = 0; mi < 4; ++mi)
            af[mi] = *(const bf16x8*)&As[(mw + mi * 16 + l16) * 32 + quad * 8];
#pragma unroll
        for (int ni = 0; ni < 4; ++ni)
            bfr[ni] = *(const bf16x8*)&Bs[(nw + ni * 16 + l16) * 32 + quad * 8];
#pragma unroll
        for (int mi = 0; mi < 4; ++mi)
#pragma unroll
            for (int ni = 0; ni < 4; ++ni)
                acc[mi][ni] = __builtin_amdgcn_mfma_f32_16x16x32_bf16(af[mi], bfr[ni], acc[mi][ni], 0, 0, 0);
    }

#pragma unroll
    for (int ni = 0; ni < 4; ++ni) {
        int ncol = ntile * 128 + nw + ni * 16 + l16;
        float bv = bias[ncol];
#pragma unroll
        for (int mi = 0; mi < 4; ++mi)
#pragma unroll
            for (int r = 0; r < 4; ++r) {
                int grow = mtile * 128 + mw + mi * 16 + quad * 4 + r;
                if (grow < M_ROWS)
                    out[(size_t)grow * C_DIM + ncol] = acc[mi][ni][r] + bv;
            }
    }
}

extern "C" void kernel_launch(void* const* d_in, const int* in_sizes, int n_in,
                              void* d_out, int out_size, void* d_ws, size_t ws_size,
                              hipStream_t stream) {
    const float* x    = (const float*)d_in[0];
    // d_in[1] = attn_bias (unused; mask computed analytically)
    const float* rc   = (const float*)d_in[2];
    const float* rs   = (const float*)d_in[3];
    const float* Wqkv = (const float*)d_in[4];
    const float* qb   = (const float*)d_in[5];
    const float* vb   = (const float*)d_in[6];
    const float* sml  = (const float*)d_in[7];
    const float* Wp   = (const float*)d_in[8];
    const float* bp   = (const float*)d_in[9];
    float* out = (float*)d_out;

    const size_t NQ   = (size_t)B_SZ * NHEADS * L_SEQ * HD;   // 5,591,040
    const size_t NVT  = (size_t)B_SZ * NHEADS * HD * LP_V;    // 5,767,168
    const size_t NX   = (size_t)M_ROWS * C_DIM;               // 5,591,040
    const size_t NWQ  = (size_t)3 * C_DIM * C_DIM;            // 3,145,728
    const size_t NWP  = (size_t)C_DIM * C_DIM;                // 1,048,576

    bf16_t* qo   = (bf16_t*)d_ws;
    bf16_t* ko   = qo + NQ;
    bf16_t* vtmp = ko + NQ;      // V in (B,H,L,hd), coalesced from qkv
    bf16_t* vo   = vtmp + NQ;    // V^T in (B,H,hd,LP_V)
    bf16_t* xb   = vo + NVT;     // reused as ao after qkv (same size NX == NQ)
    bf16_t* ao   = xb;
    bf16_t* wqb  = xb + NX;
    bf16_t* wpb  = wqb + NWQ;

    dim3 blk(256);
    const int ncvt = (N8_X + N8_WQ + N8_WP + 255) / 256;
    cvt_all<<<dim3(ncvt), blk, 0, stream>>>(x, Wqkv, Wp, xb, wqb, wpb);
    qkv_gemm<<<dim3(1032), blk, 0, stream>>>(xb, wqb, qb, vb, rc, rs, sml, qo, ko, vtmp);
    vtrans<<<dim3(22, 64), blk, 0, stream>>>(vtmp, vo);
    attn<<<dim3(704), blk, 0, stream>>>(qo, ko, vo, ao);
    proj_gemm<<<dim3(344), blk, 0, stream>>>(ao, wpb, bp, out);
}